// Round 10
// baseline (26.662 us; speedup 1.0000x reference)
//
#include <hip/hip_runtime.h>

#define B_DIM 4096
#define L_DIM 512
#define NT 1000
#define OD 8
#define TOTAL (B_DIM * L_DIM)   // 2,097,152
#define CHUNK 2048               // elements per block (4 waves x 4 rounds x 128)
#define NBLK (TOTAL / CHUNK)     // 1024 blocks = 4 blocks/CU, one batch
#define ROUNDS 4

typedef float float4n __attribute__((ext_vector_type(4)));

// Fused table: unit u = 2*idx + half (16 B), XOR-swizzled us = u ^ ((u>>3)&7)
// into 2048 units = 32 KB. Bank cluster (us%8) uniform for random idx.
__device__ __forceinline__ int swz(int u) { return u ^ ((u >> 3) & 7); }

__global__ __launch_bounds__(256) void ste_kernel(
    const float* __restrict__ timestamp,   // (B, L+1)
    const float* __restrict__ W,           // (OD, NT)
    const float* __restrict__ bias,        // (OD,)
    float* __restrict__ out_te,            // (B, L, OD)
    float* __restrict__ out_ts)            // (B, L)
{
    __shared__ float wt[2048 * 4];   // 32 KB swizzled fused table (only LDS)

    const int tid  = threadIdx.x;
    const int lane = tid & 63;
    const int wave = tid >> 6;
    const int wavebase = blockIdx.x * CHUNK + wave * (CHUNK / 4);

    // Round-0 ts loads issued FIRST (in flight during the table build).
    float tcur[2];
    #pragma unroll
    for (int u = 0; u < 2; ++u) {
        const int e   = wavebase + u * 64 + lane;
        const int row = e >> 9;              // L == 512
        const int col = e & (L_DIM - 1);
        tcur[u] = timestamp[row * (L_DIM + 1) + col];
    }

    // In-block table build: 32 independent W loads/thread (L2-broadcast
    // across blocks) + bias add + swizzled LDS writes. Overlaps the ts loads.
    #pragma unroll
    for (int j = 0; j < OD; ++j) {
        const float bj = bias[j];
        #pragma unroll
        for (int i = 0; i < 4; ++i) {
            const int r = i * 256 + tid;
            if (r < NT) {
                const float val = W[j * NT + r] + bj;
                const int u = 2 * r + (j >> 2);
                wt[swz(u) * 4 + (j & 3)] = val;
            }
        }
    }
    __syncthreads();   // the ONLY barrier

    // 4 autonomous rounds per wave, software-pipelined: round r+1's ts loads
    // are issued before round r's gather/store work. Idx exchange via
    // intra-wave __shfl (no LDS array, no extra barriers).
    const int half = lane & 1;
    const int src  = lane >> 1;
    #pragma unroll
    for (int r = 0; r < ROUNDS; ++r) {
        const int rbase = wavebase + r * 128;

        float tnext[2];
        if (r + 1 < ROUNDS) {
            #pragma unroll
            for (int u = 0; u < 2; ++u) {
                const int e   = rbase + 128 + u * 64 + lane;
                const int row = e >> 9;
                const int col = e & (L_DIM - 1);
                tnext[u] = timestamp[row * (L_DIM + 1) + col];
            }
        }

        // idx (bit-exact: IEEE div + floorf + clamp) and ts passthrough.
        int idxv[2];
        #pragma unroll
        for (int u = 0; u < 2; ++u) {
            float q = tcur[u] / 1000.0f;
            int idx = (int)floorf(q);
            idxv[u] = idx < 0 ? 0 : (idx > NT - 1 ? NT - 1 : idx);
            out_ts[rbase + u * 64 + lane] = tcur[u];            // plain store
        }

        // 4 quarters: lane l stores 16B unit (q*64 + l) of this round.
        // el = q*32 + (l>>1); its idx lives in reg q>>1 of lane (q&1)*32+(l>>1).
        #pragma unroll
        for (int q = 0; q < 4; ++q) {
            const int sidx = __shfl(idxv[q >> 1], (q & 1) * 32 + src, 64);
            const float4n v =
                *reinterpret_cast<const float4n*>(&wt[swz(2 * sidx + half) * 4]);
            *reinterpret_cast<float4n*>(
                out_te + (size_t)rbase * OD + (q * 64 + lane) * 4) = v;  // plain
        }

        if (r + 1 < ROUNDS) {
            tcur[0] = tnext[0];
            tcur[1] = tnext[1];
        }
    }
}

extern "C" void kernel_launch(void* const* d_in, const int* in_sizes, int n_in,
                              void* d_out, int out_size, void* d_ws, size_t ws_size,
                              hipStream_t stream) {
    // Inputs (setup_inputs order): input (int32, unused), timestamp (f32),
    // W (f32, 8x1000), b (f32, 8).
    const float* timestamp = (const float*)d_in[1];
    const float* W         = (const float*)d_in[2];
    const float* bias      = (const float*)d_in[3];

    float* out = (float*)d_out;
    float* out_te = out;                                    // B*L*8 floats
    float* out_ts = out + (size_t)B_DIM * L_DIM * OD;       // B*L floats

    ste_kernel<<<NBLK, 256, 0, stream>>>(timestamp, W, bias, out_te, out_ts);
}

// Round 11
// 20.104 us; speedup vs baseline: 1.3262x; 1.3262x over previous
//
#include <hip/hip_runtime.h>

#define B_DIM 4096
#define L_DIM 512
#define NT 1000
#define OD 8
#define TOTAL (B_DIM * L_DIM)   // 2,097,152
#define BLOCKT 512               // 8 waves/block
#define CHUNK 2048               // elements per block (8 waves x 2 rounds x 128)
#define NBLK (TOTAL / CHUNK)     // 1024 blocks = 4 blocks/CU x 8 waves = 32 waves/CU
#define ROUNDS 2

typedef float float4n __attribute__((ext_vector_type(4)));

// Fused table: unit u = 2*idx + half (16 B), XOR-swizzled us = u ^ ((u>>3)&7)
// into 2048 units = 32 KB. Bank cluster (us%8) uniform for random idx.
__device__ __forceinline__ int swz(int u) { return u ^ ((u >> 3) & 7); }

__global__ __launch_bounds__(512) void ste_kernel(
    const float* __restrict__ timestamp,   // (B, L+1)
    const float* __restrict__ W,           // (OD, NT)
    const float* __restrict__ bias,        // (OD,)
    float* __restrict__ out_te,            // (B, L, OD)
    float* __restrict__ out_ts)            // (B, L)
{
    __shared__ float wt[2048 * 4];   // 32 KB swizzled fused table (only LDS)

    const int tid  = threadIdx.x;
    const int lane = tid & 63;
    const int wave = tid >> 6;
    const int wavebase = blockIdx.x * CHUNK + wave * (CHUNK / 8);

    // Round-0 ts loads issued FIRST (in flight during the table build).
    float tcur[2];
    #pragma unroll
    for (int u = 0; u < 2; ++u) {
        const int e   = wavebase + u * 64 + lane;
        const int row = e >> 9;              // L == 512
        const int col = e & (L_DIM - 1);
        tcur[u] = timestamp[row * (L_DIM + 1) + col];
    }

    // In-block table build: 16 independent W loads/thread (L2-broadcast
    // across blocks) + bias add + swizzled LDS writes. Overlaps the ts loads.
    #pragma unroll
    for (int j = 0; j < OD; ++j) {
        const float bj = bias[j];
        #pragma unroll
        for (int i = 0; i < 2; ++i) {
            const int r = i * 512 + tid;
            if (r < NT) {
                const float val = W[j * NT + r] + bj;
                const int u = 2 * r + (j >> 2);
                wt[swz(u) * 4 + (j & 3)] = val;
            }
        }
    }
    __syncthreads();   // the ONLY barrier

    // 2 autonomous rounds per wave, software-pipelined: round r+1's ts loads
    // are issued before round r's gather/store work. Idx exchange via
    // intra-wave __shfl (no LDS array, no extra barriers).
    const int half = lane & 1;
    const int src  = lane >> 1;
    #pragma unroll
    for (int r = 0; r < ROUNDS; ++r) {
        const int rbase = wavebase + r * 128;

        float tnext[2];
        if (r + 1 < ROUNDS) {
            #pragma unroll
            for (int u = 0; u < 2; ++u) {
                const int e   = rbase + 128 + u * 64 + lane;
                const int row = e >> 9;
                const int col = e & (L_DIM - 1);
                tnext[u] = timestamp[row * (L_DIM + 1) + col];
            }
        }

        // idx (bit-exact: IEEE div + floorf + clamp) and ts passthrough.
        int idxv[2];
        #pragma unroll
        for (int u = 0; u < 2; ++u) {
            float q = tcur[u] / 1000.0f;
            int idx = (int)floorf(q);
            idxv[u] = idx < 0 ? 0 : (idx > NT - 1 ? NT - 1 : idx);
            __builtin_nontemporal_store(tcur[u], &out_ts[rbase + u * 64 + lane]);
        }

        // 4 quarters: lane l stores 16B unit (q*64 + l) of this round.
        // el = q*32 + (l>>1); its idx lives in reg q>>1 of lane (q&1)*32+(l>>1).
        #pragma unroll
        for (int q = 0; q < 4; ++q) {
            const int sidx = __shfl(idxv[q >> 1], (q & 1) * 32 + src, 64);
            const float4n v =
                *reinterpret_cast<const float4n*>(&wt[swz(2 * sidx + half) * 4]);
            __builtin_nontemporal_store(
                v, reinterpret_cast<float4n*>(
                       out_te + (size_t)rbase * OD + (q * 64 + lane) * 4));
        }

        if (r + 1 < ROUNDS) {
            tcur[0] = tnext[0];
            tcur[1] = tnext[1];
        }
    }
}

extern "C" void kernel_launch(void* const* d_in, const int* in_sizes, int n_in,
                              void* d_out, int out_size, void* d_ws, size_t ws_size,
                              hipStream_t stream) {
    // Inputs (setup_inputs order): input (int32, unused), timestamp (f32),
    // W (f32, 8x1000), b (f32, 8).
    const float* timestamp = (const float*)d_in[1];
    const float* W         = (const float*)d_in[2];
    const float* bias      = (const float*)d_in[3];

    float* out = (float*)d_out;
    float* out_te = out;                                    // B*L*8 floats
    float* out_ts = out + (size_t)B_DIM * L_DIM * OD;       // B*L floats

    ste_kernel<<<NBLK, BLOCKT, 0, stream>>>(timestamp, W, bias, out_te, out_ts);
}

// Round 12
// 19.217 us; speedup vs baseline: 1.3875x; 1.0462x over previous
//
#include <hip/hip_runtime.h>

#define B_DIM 4096
#define L_DIM 512
#define NT 1000
#define OD 8
#define TOTAL (B_DIM * L_DIM)   // 2,097,152
#define BLOCKT 1024              // 16 waves/block
#define CHUNK 4096               // elements per block (16 waves x 2 rounds x 128)
#define NBLK (TOTAL / CHUNK)     // 512 blocks = 2 blocks/CU x 16 waves = 32 waves/CU
#define ROUNDS 2

typedef float float4n __attribute__((ext_vector_type(4)));

// Fused table: unit u = 2*idx + half (16 B), XOR-swizzled us = u ^ ((u>>3)&7)
// into 2048 units = 32 KB. Bank cluster (us%8) uniform for random idx.
__device__ __forceinline__ int swz(int u) { return u ^ ((u >> 3) & 7); }

__global__ __launch_bounds__(1024) void ste_kernel(
    const float* __restrict__ timestamp,   // (B, L+1)
    const float* __restrict__ W,           // (OD, NT)
    const float* __restrict__ bias,        // (OD,)
    float* __restrict__ out_te,            // (B, L, OD)
    float* __restrict__ out_ts)            // (B, L)
{
    __shared__ float wt[2048 * 4];   // 32 KB swizzled fused table (only LDS)

    const int tid  = threadIdx.x;
    const int lane = tid & 63;
    const int wave = tid >> 6;
    const int wavebase = blockIdx.x * CHUNK + wave * (CHUNK / 16);

    // Round-0 ts loads issued FIRST (in flight during the table build).
    float tcur[2];
    #pragma unroll
    for (int u = 0; u < 2; ++u) {
        const int e   = wavebase + u * 64 + lane;
        const int row = e >> 9;              // L == 512
        const int col = e & (L_DIM - 1);
        tcur[u] = timestamp[row * (L_DIM + 1) + col];
    }

    // In-block table build: 8 independent W loads/thread (L2-broadcast
    // across blocks) + bias add + swizzled LDS writes. Overlaps the ts loads.
    #pragma unroll
    for (int j = 0; j < OD; ++j) {
        const float bj = bias[j];
        const int r = tid;                   // 1024 threads cover 0..999 in one step
        if (r < NT) {
            const float val = W[j * NT + r] + bj;
            const int u = 2 * r + (j >> 2);
            wt[swz(u) * 4 + (j & 3)] = val;
        }
    }
    __syncthreads();   // the ONLY barrier

    // 2 autonomous rounds per wave, software-pipelined: round r+1's ts loads
    // are issued before round r's gather/store work. Idx exchange via
    // intra-wave __shfl (no LDS array, no extra barriers).
    const int half = lane & 1;
    const int src  = lane >> 1;
    #pragma unroll
    for (int r = 0; r < ROUNDS; ++r) {
        const int rbase = wavebase + r * 128;

        float tnext[2];
        if (r + 1 < ROUNDS) {
            #pragma unroll
            for (int u = 0; u < 2; ++u) {
                const int e   = rbase + 128 + u * 64 + lane;
                const int row = e >> 9;
                const int col = e & (L_DIM - 1);
                tnext[u] = timestamp[row * (L_DIM + 1) + col];
            }
        }

        // idx (bit-exact: IEEE div + floorf + clamp) and ts passthrough.
        int idxv[2];
        #pragma unroll
        for (int u = 0; u < 2; ++u) {
            float q = tcur[u] / 1000.0f;
            int idx = (int)floorf(q);
            idxv[u] = idx < 0 ? 0 : (idx > NT - 1 ? NT - 1 : idx);
            __builtin_nontemporal_store(tcur[u], &out_ts[rbase + u * 64 + lane]);
        }

        // 4 quarters: lane l stores 16B unit (q*64 + l) of this round.
        // el = q*32 + (l>>1); its idx lives in reg q>>1 of lane (q&1)*32+(l>>1).
        #pragma unroll
        for (int q = 0; q < 4; ++q) {
            const int sidx = __shfl(idxv[q >> 1], (q & 1) * 32 + src, 64);
            const float4n v =
                *reinterpret_cast<const float4n*>(&wt[swz(2 * sidx + half) * 4]);
            __builtin_nontemporal_store(
                v, reinterpret_cast<float4n*>(
                       out_te + (size_t)rbase * OD + (q * 64 + lane) * 4));
        }

        if (r + 1 < ROUNDS) {
            tcur[0] = tnext[0];
            tcur[1] = tnext[1];
        }
    }
}

extern "C" void kernel_launch(void* const* d_in, const int* in_sizes, int n_in,
                              void* d_out, int out_size, void* d_ws, size_t ws_size,
                              hipStream_t stream) {
    // Inputs (setup_inputs order): input (int32, unused), timestamp (f32),
    // W (f32, 8x1000), b (f32, 8).
    const float* timestamp = (const float*)d_in[1];
    const float* W         = (const float*)d_in[2];
    const float* bias      = (const float*)d_in[3];

    float* out = (float*)d_out;
    float* out_te = out;                                    // B*L*8 floats
    float* out_ts = out + (size_t)B_DIM * L_DIM * OD;       // B*L floats

    ste_kernel<<<NBLK, BLOCKT, 0, stream>>>(timestamp, W, bias, out_te, out_ts);
}